// Round 17
// baseline (308.355 us; speedup 1.0000x reference)
//
#include <hip/hip_runtime.h>
#include <cstdint>
#include <cstddef>

#define DD 256
#define NSLOT 25      // gslot: 0..11 fwd rel | 12 self | 13..24 rev rel
#define SELFSLOT 12

typedef unsigned short u16;
typedef __bf16 bf16t;
typedef bf16t bf16x8 __attribute__((ext_vector_type(8)));
typedef unsigned short us8 __attribute__((ext_vector_type(8)));
typedef unsigned short us4 __attribute__((ext_vector_type(4)));
typedef float f32x4 __attribute__((ext_vector_type(4)));

__device__ __forceinline__ u16 f2bf(float f) {
    uint32_t u = __builtin_bit_cast(uint32_t, f);
    u += 0x7FFFu + ((u >> 16) & 1u);   // RNE
    return (u16)(u >> 16);
}
__device__ __forceinline__ float bf2f(u16 h) {
    uint32_t u = ((uint32_t)h) << 16;
    return __builtin_bit_cast(float, u);
}

// fused prep: blocks [0,1024) convert x/W/bias (float4-vectorized);
// blocks [1024,1536) mark+hist edge pass
__global__ void k_prep(const float* __restrict__ x, const float* __restrict__ W_rel,
                       const float* __restrict__ W_self, const float* __restrict__ b_self,
                       const float* __restrict__ b_rel,
                       u16* __restrict__ xb, u16* __restrict__ Wb, float* __restrict__ ba,
                       const int* __restrict__ dep, const int* __restrict__ rel,
                       const int* __restrict__ gov, int E, int N, int SG,
                       int* __restrict__ flag, int* __restrict__ bcnt, int NDD) {
    if (blockIdx.x < 1024) {
        const int s0 = NDD;                 // x
        const int s1 = s0 + 12 * 65536;     // W_rel fwd
        const int s2 = s1 + 65536;          // W_self
        const int s3 = s2 + 12 * 65536;     // W_rel rev
        const int s4 = s3 + NSLOT * DD;     // bias (all boundaries %4 == 0)
        const int t4 = s4 >> 2;
        int i = blockIdx.x * 256 + threadIdx.x;
        const int st = 1024 * 256;
        for (; i < t4; i += st) {
            int e = i << 2;
            const float* src; u16* dst;
            if (e < s0)      { src = x + e;                    dst = xb + e; }
            else if (e < s1) { src = W_rel + (e - s0);         dst = Wb + (e - s0); }
            else if (e < s2) { src = W_self + (e - s1);        dst = Wb + 12 * 65536 + (e - s1); }
            else if (e < s3) { src = W_rel + 12 * 65536 + (e - s2); dst = Wb + 13 * 65536 + (e - s2); }
            else {
                int k = e - s3;   // bias: sub-boundaries 3072, 3328 are %4 == 0
                const float* bsrc;
                if (k < 12 * DD) bsrc = b_rel + k;
                else if (k < 13 * DD) bsrc = b_self + (k - 12 * DD);
                else bsrc = b_rel + (k - DD);
                *(f32x4*)(ba + k) = *(const f32x4*)bsrc;
                continue;
            }
            f32x4 v = *(const f32x4*)src;
            us4 o;
            #pragma unroll
            for (int j = 0; j < 4; ++j) o[j] = f2bf(v[j]);
            *(us4*)dst = o;
        }
    } else {
        int i = (blockIdx.x - 1024) * 256 + threadIdx.x;
        int st = 512 * 256;
        for (int j = i; j < E; j += st) {
            int r = rel[j], d = dep[j], g = gov[j];
            flag[r * N + g] = 1;
            flag[(13 + r) * N + d] = 1;
            atomicAdd(&bcnt[(r / SG) * N + d], 1);
            atomicAdd(&bcnt[((13 + r) / SG) * N + g], 1);
        }
        for (int j = i; j < N; j += st) flag[SELFSLOT * N + j] = 1;
    }
}

// dual per-block local scan: blocks [0,nbA) scan A (len lenA), rest scan B (len lenB)
__global__ void k_scan1d(const int* __restrict__ A, int* __restrict__ outA,
                         int* __restrict__ bsumA, int lenA, int nbA,
                         const int* __restrict__ B, int* __restrict__ outB,
                         int* __restrict__ bsumB, int lenB) {
    __shared__ int sm[256];
    const int* in; int* outp; int* bs; int len; int lb;
    if ((int)blockIdx.x < nbA) { in = A; outp = outA; bs = bsumA; len = lenA; lb = blockIdx.x; }
    else { in = B; outp = outB; bs = bsumB; len = lenB; lb = blockIdx.x - nbA; }
    int tid = threadIdx.x;
    int i = lb * 256 + tid;
    int v = (i < len) ? in[i] : 0;
    sm[tid] = v;
    __syncthreads();
    for (int off = 1; off < 256; off <<= 1) {
        int t = (tid >= off) ? sm[tid - off] : 0;
        __syncthreads();
        sm[tid] += t;
        __syncthreads();
    }
    if (i < len) outp[i] = sm[tid] - v;
    if (tid == 255) bs[lb] = sm[255];
}

// single block scans both block-total arrays (each <= 2048)
__global__ void k_scan2d(const int* __restrict__ bsumA, int* __restrict__ bbasA, int nbA,
                         const int* __restrict__ bsumB, int* __restrict__ bbasB, int nbB) {
    __shared__ int sm[256];
    int t = threadIdx.x;
    for (int which = 0; which < 2; ++which) {
        const int* bsum = which ? bsumB : bsumA;
        int* bbase = which ? bbasB : bbasA;
        int nb = which ? nbB : nbA;
        int pre[8];
        int tot = 0;
        for (int j = 0; j < 8; ++j) {
            int idx = t * 8 + j;
            int v = (idx < nb) ? bsum[idx] : 0;
            pre[j] = tot;
            tot += v;
        }
        sm[t] = tot;
        __syncthreads();
        for (int off = 1; off < 256; off <<= 1) {
            int x = (t >= off) ? sm[t - off] : 0;
            __syncthreads();
            sm[t] += x;
            __syncthreads();
        }
        int base = sm[t] - tot;
        for (int j = 0; j < 8; ++j) {
            int idx = t * 8 + j;
            if (idx < nb) bbase[idx] = base + pre[j];
        }
        __syncthreads();
    }
}

// fused finalize: pos(+sentinel)+rksrc for flags; bcsr/bcur(+sentinel) for buckets
__global__ void k_scan3d(int* __restrict__ pos, const int* __restrict__ bbasA,
                         const int* __restrict__ flag, int NN, int N,
                         int* __restrict__ rksrc,
                         int* __restrict__ bcsr, int* __restrict__ bcur,
                         const int* __restrict__ bbasB, int B2, int E2) {
    int i = blockIdx.x * 256 + threadIdx.x;
    if (i < NN) {
        int v = pos[i] + bbasA[i >> 8];
        pos[i] = v;
        if (i == NN - 1) pos[NN] = v + flag[i];
        if (flag[i]) {
            int slot = i / N;
            rksrc[v] = i - slot * N;
        }
    }
    if (i < B2) {
        int v = bcsr[i] + bbasB[i >> 8];
        bcsr[i] = v;
        bcur[i] = v;
    }
    if (i == 0) bcsr[B2] = E2;
}

// Compacted GEMM + optional fused edge-scatter blocks (bx < nScat, placed first).
// 128x128 tile (4 waves x 64x64), K=256, mtile-major block order, swapped operands.
// LDS: XOR-swizzled (chunk c of row r at c^(r&7)) -> no padding, 32 KB, 5 blocks/CU.
// elem(row,k) at row*64 + (((k>>3)^(row&7))<<3) + (k&7)
__global__ __launch_bounds__(256, 5) void k_T(
    const u16* __restrict__ xb, const u16* __restrict__ Wb, const float* __restrict__ ba,
    const int* __restrict__ pos, const int* __restrict__ rksrc, u16* __restrict__ T,
    int N, int gslot0, int Sg,
    const int* __restrict__ dep, const int* __restrict__ rel, const int* __restrict__ gov,
    int E, int SG, int* __restrict__ bcur, int* __restrict__ epay, int nScat) {
    __shared__ u16 sm[2 * 128 * 64];     // As | Bs, swizzled; reused for transpose
    u16* As = sm;
    u16* Bs = sm + 128 * 64;

    const int tid = threadIdx.x;
    if ((int)blockIdx.x < nScat) {
        // ---- scatter role: payload = group-local compacted T row ----
        int i = blockIdx.x * 256 + tid;
        int st = nScat * 256;
        for (; i < E; i += st) {
            int r = rel[i], d = dep[i], g = gov[i];
            int g0 = r / SG;
            int p = atomicAdd(&bcur[g0 * N + d], 1);
            epay[p] = pos[r * N + g] - pos[g0 * SG * N];
            int gs = 13 + r;
            int g1 = gs / SG;
            int q = atomicAdd(&bcur[g1 * N + g], 1);
            epay[q] = pos[gs * N + d] - pos[g1 * SG * N];
        }
        return;
    }

    const int bx = blockIdx.x - nScat;
    const int mtile = bx / (2 * Sg);
    const int rem = bx - mtile * 2 * Sg;
    const int slot = rem >> 1;
    const int n0 = (rem & 1) * 128;
    const int gslot = gslot0 + slot;
    const int u0 = pos[gslot * N];
    const int used = pos[(gslot + 1) * N] - u0;
    const int row0 = mtile * 128;
    if (row0 >= used) return;
    const int gbase = pos[gslot0 * N];

    const int lane = tid & 63, wv = tid >> 6;
    const int wr = wv & 1, wc = wv >> 1;
    const int l15 = lane & 15, quad = lane >> 4;
    const int srow = tid >> 1, sh = (tid & 1) * 32;

    // per-thread source row (no LDS broadcast needed: only this thread stages srow)
    int arow = row0 + srow;
    if (arow >= used) arow = used - 1;
    const int asrc = rksrc[u0 + arow];
    const u16* agp = xb + (size_t)asrc * DD + sh;
    const u16* bgp = Wb + ((size_t)gslot << 16) + (size_t)(n0 + srow) * DD + sh;

    const int sc0 = sh >> 3;          // first logical chunk (0 or 4)
    const int sx = srow & 7;
    int so[4];                        // physical u16 offsets for the 4 staged chunks
    #pragma unroll
    for (int c = 0; c < 4; ++c) so[c] = srow * 64 + (((sc0 + c) ^ sx) << 3);

    f32x4 acc[4][4] = {};   // acc[nt][mt] = D[n-tile][m-tile] (swapped operands)
    for (int kb = 0; kb < DD; kb += 64) {
        {
            const us8* ga = (const us8*)(agp + kb);
            us8 a0 = ga[0], a1 = ga[1], a2 = ga[2], a3 = ga[3];
            *(us8*)&As[so[0]] = a0;
            *(us8*)&As[so[1]] = a1;
            *(us8*)&As[so[2]] = a2;
            *(us8*)&As[so[3]] = a3;
            const us8* gb = (const us8*)(bgp + kb);
            us8 b0 = gb[0], b1 = gb[1], b2 = gb[2], b3 = gb[3];
            *(us8*)&Bs[so[0]] = b0;
            *(us8*)&Bs[so[1]] = b1;
            *(us8*)&Bs[so[2]] = b2;
            *(us8*)&Bs[so[3]] = b3;
        }
        __syncthreads();
        #pragma unroll
        for (int ks = 0; ks < 2; ++ks) {
            const int ck = ks * 4 + quad;             // logical chunk of this frag
            bf16x8 af[4], bfv[4];
            #pragma unroll
            for (int mt = 0; mt < 4; ++mt) {
                int r = wr * 64 + mt * 16 + l15;
                af[mt] = __builtin_bit_cast(bf16x8,
                    *(const us8*)&As[r * 64 + ((ck ^ (r & 7)) << 3)]);
            }
            #pragma unroll
            for (int nt = 0; nt < 4; ++nt) {
                int r = wc * 64 + nt * 16 + l15;
                bfv[nt] = __builtin_bit_cast(bf16x8,
                    *(const us8*)&Bs[r * 64 + ((ck ^ (r & 7)) << 3)]);
            }
            #pragma unroll
            for (int nt = 0; nt < 4; ++nt)
                #pragma unroll
                for (int mt = 0; mt < 4; ++mt)
                    acc[nt][mt] = __builtin_amdgcn_mfma_f32_16x16x32_bf16(
                        bfv[nt], af[mt], acc[nt][mt], 0, 0, 0);
        }
        __syncthreads();
    }

    // epilogue: +bias (f32x4), bf16, swizzled b64 LDS transpose, b128 global stores
    f32x4 bb[4];
    #pragma unroll
    for (int nt = 0; nt < 4; ++nt)
        bb[nt] = *(const f32x4*)(ba + gslot * DD + n0 + wc * 64 + nt * 16 + quad * 4);
    u16* trb = sm + wv * 4096;        // per-wave 64 rows x 64 cols, swizzled
    #pragma unroll
    for (int mt = 0; mt < 4; ++mt) {
        int m = mt * 16 + l15;
        int mx = m & 7;
        #pragma unroll
        for (int nt = 0; nt < 4; ++nt) {
            us4 t4;
            #pragma unroll
            for (int j = 0; j < 4; ++j) t4[j] = f2bf(acc[nt][mt][j] + bb[nt][j]);
            int col = nt * 16 + quad * 4;
            *(us4*)&trb[m * 64 + (((col >> 3) ^ mx) << 3) + (col & 7)] = t4;
        }
    }
    __syncthreads();
    const int trow0 = u0 - gbase + row0 + wr * 64;
    const int half = lane & 1;
    #pragma unroll
    for (int it = 0; it < 2; ++it) {
        int r = it * 32 + (lane >> 1);
        if (row0 + wr * 64 + r < used) {
            int rx = r & 7;
            us8 v0 = *(const us8*)&trb[r * 64 + (((half * 4 + 0) ^ rx) << 3)];
            us8 v1 = *(const us8*)&trb[r * 64 + (((half * 4 + 1) ^ rx) << 3)];
            us8 v2 = *(const us8*)&trb[r * 64 + (((half * 4 + 2) ^ rx) << 3)];
            us8 v3 = *(const us8*)&trb[r * 64 + (((half * 4 + 3) ^ rx) << 3)];
            us8* dp = (us8*)(T + (size_t)(trow0 + r) * DD + n0 + wc * 64 + half * 32);
            dp[0] = v0; dp[1] = v1; dp[2] = v2; dp[3] = v3;
        }
    }
}

// Gather: one wave per node; lane owns 4 feats; 8-deep load unroll for MLP.
__global__ __launch_bounds__(256) void k_gather(
    const u16* __restrict__ T, const int* __restrict__ epay,
    const int* __restrict__ csr, const int* __restrict__ pos,
    float* __restrict__ out, int N, int bktBase, int selfKeyBase, int gfN,
    int first, int last) {
    int wid = (blockIdx.x * 256 + threadIdx.x) >> 6;
    if (wid >= N) return;
    int feat = (threadIdx.x & 63) * 4;
    f32x4 a = {0.0f, 0.0f, 0.0f, 0.0f};
    if (!first) a = *(const f32x4*)(out + (size_t)wid * DD + feat);
    if (selfKeyBase >= 0) {
        int p = pos[selfKeyBase + wid] - pos[gfN];
        us4 v = *(const us4*)(T + (size_t)p * DD + feat);
        a[0] += bf2f(v[0]); a[1] += bf2f(v[1]); a[2] += bf2f(v[2]); a[3] += bf2f(v[3]);
    }
    int beg = csr[bktBase + wid], end = csr[bktBase + wid + 1];
    f32x4 b = {0, 0, 0, 0}, c = {0, 0, 0, 0}, d4 = {0, 0, 0, 0};
    int j = beg;
    for (; j + 7 < end; j += 8) {
        int p0 = epay[j],     p1 = epay[j + 1], p2 = epay[j + 2], p3 = epay[j + 3];
        int p4 = epay[j + 4], p5 = epay[j + 5], p6 = epay[j + 6], p7 = epay[j + 7];
        us4 v0 = *(const us4*)(T + (size_t)p0 * DD + feat);
        us4 v1 = *(const us4*)(T + (size_t)p1 * DD + feat);
        us4 v2 = *(const us4*)(T + (size_t)p2 * DD + feat);
        us4 v3 = *(const us4*)(T + (size_t)p3 * DD + feat);
        us4 v4 = *(const us4*)(T + (size_t)p4 * DD + feat);
        us4 v5 = *(const us4*)(T + (size_t)p5 * DD + feat);
        us4 v6 = *(const us4*)(T + (size_t)p6 * DD + feat);
        us4 v7 = *(const us4*)(T + (size_t)p7 * DD + feat);
        #pragma unroll
        for (int t = 0; t < 4; ++t) {
            a[t]  += bf2f(v0[t]) + bf2f(v4[t]);
            b[t]  += bf2f(v1[t]) + bf2f(v5[t]);
            c[t]  += bf2f(v2[t]) + bf2f(v6[t]);
            d4[t] += bf2f(v3[t]) + bf2f(v7[t]);
        }
    }
    for (; j + 1 < end; j += 2) {
        int p0 = epay[j], p1 = epay[j + 1];
        us4 v0 = *(const us4*)(T + (size_t)p0 * DD + feat);
        us4 v1 = *(const us4*)(T + (size_t)p1 * DD + feat);
        #pragma unroll
        for (int t = 0; t < 4; ++t) { a[t] += bf2f(v0[t]); b[t] += bf2f(v1[t]); }
    }
    if (j < end) {
        int p0 = epay[j];
        us4 v0 = *(const us4*)(T + (size_t)p0 * DD + feat);
        #pragma unroll
        for (int t = 0; t < 4; ++t) a[t] += bf2f(v0[t]);
    }
    #pragma unroll
    for (int t = 0; t < 4; ++t) a[t] += b[t] + c[t] + d4[t];
    if (last) {
        #pragma unroll
        for (int t = 0; t < 4; ++t) a[t] = fmaxf(a[t], 0.0f);
    }
    *(f32x4*)(out + (size_t)wid * DD + feat) = a;
}

extern "C" void kernel_launch(void* const* d_in, const int* in_sizes, int n_in,
                              void* d_out, int out_size, void* d_ws, size_t ws_size,
                              hipStream_t stream) {
    const float* x      = (const float*)d_in[0];
    const int*   dep    = (const int*)  d_in[1];
    const int*   rel    = (const int*)  d_in[2];
    const int*   gov    = (const int*)  d_in[3];
    const float* W_self = (const float*)d_in[4];
    const float* b_self = (const float*)d_in[5];
    const float* W_rel  = (const float*)d_in[6];
    const float* b_rel  = (const float*)d_in[7];
    float* out = (float*)d_out;

    const int N  = in_sizes[0] / DD;     // 20000
    const int E  = in_sizes[1];          // 200000
    const int NN = NSLOT * N;            // 500000 keys

    char* w = (char*)d_ws;
    auto alloc = [&](size_t bytes) {
        char* p = w;
        w += (bytes + 255) & ~(size_t)255;
        return p;
    };
    u16* xb    = (u16*)alloc((size_t)N * DD * sizeof(u16));
    u16* Wb    = (u16*)alloc((size_t)NSLOT * DD * DD * sizeof(u16));
    float* ba  = (float*)alloc((size_t)NSLOT * DD * sizeof(float));
    int* flag  = (int*)alloc((size_t)NN * sizeof(int));
    int* pos   = (int*)alloc(((size_t)NN + 1) * sizeof(int));
    int* rksrc = (int*)alloc(((size_t)2 * E + N) * sizeof(int));
    int* bcnt  = (int*)alloc((size_t)6 * N * sizeof(int));
    int* bcsr  = (int*)alloc(((size_t)6 * N + 1) * sizeof(int));
    int* bcur  = (int*)alloc((size_t)6 * N * sizeof(int));
    int* bsumA = (int*)alloc((size_t)2048 * sizeof(int));
    int* bbasA = (int*)alloc((size_t)2048 * sizeof(int));
    int* bsumB = (int*)alloc((size_t)2048 * sizeof(int));
    int* bbasB = (int*)alloc((size_t)2048 * sizeof(int));
    int* epay  = (int*)alloc((size_t)2 * E * sizeof(int));

    size_t used = (size_t)(w - (char*)d_ws);
    size_t avail = (ws_size > used) ? (ws_size - used) : 0;

    // choose group count: tight worst-case T rows per group (prefer 1 group)
    int NGROUP = 2, SG = 13;
    for (int ng = 1; ng <= 5; ++ng) {
        int sg = (NSLOT + ng - 1) / ng;
        size_t maxB = 0;
        for (int g = 0; g < ng; ++g) {
            int s0 = g * sg, s1 = s0 + sg; if (s1 > NSLOT) s1 = NSLOT;
            if (s0 >= NSLOT) break;
            int hasSelf = (s0 <= SELFSLOT && SELFSLOT < s1) ? 1 : 0;
            size_t rels = (size_t)(s1 - s0 - hasSelf);
            size_t rows = rels * N; if (rows > (size_t)2 * E) rows = (size_t)2 * E;
            rows += hasSelf ? (size_t)N : 0;
            if (rows > maxB) maxB = rows;
        }
        if (maxB * ((size_t)DD * 2) <= avail) { NGROUP = ng; SG = sg; break; }
        NGROUP = ng + 1; SG = (NSLOT + NGROUP - 1) / NGROUP;
    }
    u16* T = (u16*)w;
    const int B2 = NGROUP * N;

    // 1. zero via DMA, then fused converts ∥ mark+hist (1 dispatch)
    hipMemsetAsync(flag, 0, (size_t)NN * sizeof(int), stream);
    hipMemsetAsync(bcnt, 0, (size_t)B2 * sizeof(int), stream);
    k_prep<<<1536, 256, 0, stream>>>(x, W_rel, W_self, b_self, b_rel, xb, Wb, ba,
                                     dep, rel, gov, E, N, SG, flag, bcnt, N * DD);

    // 2. dual scan: flags (NN) + buckets (B2)
    const int nbA = (NN + 255) / 256;
    const int nbB = (B2 + 255) / 256;
    k_scan1d<<<nbA + nbB, 256, 0, stream>>>(flag, pos, bsumA, NN, nbA, bcnt, bcsr, bsumB, B2);
    k_scan2d<<<1, 256, 0, stream>>>(bsumA, bbasA, nbA, bsumB, bbasB, nbB);
    k_scan3d<<<nbA, 256, 0, stream>>>(pos, bbasA, flag, NN, N, rksrc, bcsr, bcur, bbasB, B2, 2 * E);

    // 3. per group: compacted GEMM (scatter fused into first dispatch) -> gather (+relu last)
    const int tilesPerSlot = (N + 127) / 128;
    const int gBlocks = (N + 3) / 4;
    for (int g = 0; g < NGROUP; ++g) {
        int s0 = g * SG;
        if (s0 >= NSLOT) break;
        int Sg = NSLOT - s0; if (Sg > SG) Sg = SG;
        int nScat = (g == 0) ? 256 : 0;
        k_T<<<dim3(nScat + tilesPerSlot * Sg * 2), 256, 0, stream>>>(
            xb, Wb, ba, pos, rksrc, T, N, s0, Sg,
            dep, rel, gov, E, SG, bcur, epay, nScat);
        int hasSelf = (s0 <= SELFSLOT && SELFSLOT < s0 + Sg);
        k_gather<<<gBlocks, 256, 0, stream>>>(
            T, epay, bcsr, pos, out, N, g * N,
            hasSelf ? SELFSLOT * N : -1, s0 * N,
            (g == 0) ? 1 : 0, (g == NGROUP - 1) ? 1 : 0);
    }
}

// Round 18
// 250.439 us; speedup vs baseline: 1.2313x; 1.2313x over previous
//
#include <hip/hip_runtime.h>
#include <cstdint>
#include <cstddef>

#define DD 256
#define NSLOT 25      // gslot: 0..11 fwd rel | 12 self | 13..24 rev rel
#define SELFSLOT 12

typedef unsigned short u16;
typedef __bf16 bf16t;
typedef bf16t bf16x8 __attribute__((ext_vector_type(8)));
typedef unsigned short us8 __attribute__((ext_vector_type(8)));
typedef unsigned short us4 __attribute__((ext_vector_type(4)));
typedef float f32x4 __attribute__((ext_vector_type(4)));

__device__ __forceinline__ u16 f2bf(float f) {
    uint32_t u = __builtin_bit_cast(uint32_t, f);
    u += 0x7FFFu + ((u >> 16) & 1u);   // RNE
    return (u16)(u >> 16);
}
__device__ __forceinline__ float bf2f(u16 h) {
    uint32_t u = ((uint32_t)h) << 16;
    return __builtin_bit_cast(float, u);
}

// fused prep: blocks [0,1024) convert x/W/bias (float4-vectorized);
// blocks [1024,1536) mark+hist edge pass
__global__ void k_prep(const float* __restrict__ x, const float* __restrict__ W_rel,
                       const float* __restrict__ W_self, const float* __restrict__ b_self,
                       const float* __restrict__ b_rel,
                       u16* __restrict__ xb, u16* __restrict__ Wb, float* __restrict__ ba,
                       const int* __restrict__ dep, const int* __restrict__ rel,
                       const int* __restrict__ gov, int E, int N, int SG,
                       int* __restrict__ flag, int* __restrict__ bcnt, int NDD) {
    if (blockIdx.x < 1024) {
        const int s0 = NDD;                 // x
        const int s1 = s0 + 12 * 65536;     // W_rel fwd
        const int s2 = s1 + 65536;          // W_self
        const int s3 = s2 + 12 * 65536;     // W_rel rev
        const int s4 = s3 + NSLOT * DD;     // bias (all boundaries %4 == 0)
        const int t4 = s4 >> 2;
        int i = blockIdx.x * 256 + threadIdx.x;
        const int st = 1024 * 256;
        for (; i < t4; i += st) {
            int e = i << 2;
            const float* src; u16* dst;
            if (e < s0)      { src = x + e;                    dst = xb + e; }
            else if (e < s1) { src = W_rel + (e - s0);         dst = Wb + (e - s0); }
            else if (e < s2) { src = W_self + (e - s1);        dst = Wb + 12 * 65536 + (e - s1); }
            else if (e < s3) { src = W_rel + 12 * 65536 + (e - s2); dst = Wb + 13 * 65536 + (e - s2); }
            else {
                int k = e - s3;   // bias: sub-boundaries 3072, 3328 are %4 == 0
                const float* bsrc;
                if (k < 12 * DD) bsrc = b_rel + k;
                else if (k < 13 * DD) bsrc = b_self + (k - 12 * DD);
                else bsrc = b_rel + (k - DD);
                *(f32x4*)(ba + k) = *(const f32x4*)bsrc;
                continue;
            }
            f32x4 v = *(const f32x4*)src;
            us4 o;
            #pragma unroll
            for (int j = 0; j < 4; ++j) o[j] = f2bf(v[j]);
            *(us4*)dst = o;
        }
    } else {
        int i = (blockIdx.x - 1024) * 256 + threadIdx.x;
        int st = 512 * 256;
        for (int j = i; j < E; j += st) {
            int r = rel[j], d = dep[j], g = gov[j];
            flag[r * N + g] = 1;
            flag[(13 + r) * N + d] = 1;
            atomicAdd(&bcnt[(r / SG) * N + d], 1);
            atomicAdd(&bcnt[((13 + r) / SG) * N + g], 1);
        }
        for (int j = i; j < N; j += st) flag[SELFSLOT * N + j] = 1;
    }
}

// dual per-block local scan: blocks [0,nbA) scan A (len lenA), rest scan B (len lenB)
__global__ void k_scan1d(const int* __restrict__ A, int* __restrict__ outA,
                         int* __restrict__ bsumA, int lenA, int nbA,
                         const int* __restrict__ B, int* __restrict__ outB,
                         int* __restrict__ bsumB, int lenB) {
    __shared__ int sm[256];
    const int* in; int* outp; int* bs; int len; int lb;
    if ((int)blockIdx.x < nbA) { in = A; outp = outA; bs = bsumA; len = lenA; lb = blockIdx.x; }
    else { in = B; outp = outB; bs = bsumB; len = lenB; lb = blockIdx.x - nbA; }
    int tid = threadIdx.x;
    int i = lb * 256 + tid;
    int v = (i < len) ? in[i] : 0;
    sm[tid] = v;
    __syncthreads();
    for (int off = 1; off < 256; off <<= 1) {
        int t = (tid >= off) ? sm[tid - off] : 0;
        __syncthreads();
        sm[tid] += t;
        __syncthreads();
    }
    if (i < len) outp[i] = sm[tid] - v;
    if (tid == 255) bs[lb] = sm[255];
}

// single block scans both block-total arrays (each <= 2048)
__global__ void k_scan2d(const int* __restrict__ bsumA, int* __restrict__ bbasA, int nbA,
                         const int* __restrict__ bsumB, int* __restrict__ bbasB, int nbB) {
    __shared__ int sm[256];
    int t = threadIdx.x;
    for (int which = 0; which < 2; ++which) {
        const int* bsum = which ? bsumB : bsumA;
        int* bbase = which ? bbasB : bbasA;
        int nb = which ? nbB : nbA;
        int pre[8];
        int tot = 0;
        for (int j = 0; j < 8; ++j) {
            int idx = t * 8 + j;
            int v = (idx < nb) ? bsum[idx] : 0;
            pre[j] = tot;
            tot += v;
        }
        sm[t] = tot;
        __syncthreads();
        for (int off = 1; off < 256; off <<= 1) {
            int x = (t >= off) ? sm[t - off] : 0;
            __syncthreads();
            sm[t] += x;
            __syncthreads();
        }
        int base = sm[t] - tot;
        for (int j = 0; j < 8; ++j) {
            int idx = t * 8 + j;
            if (idx < nb) bbase[idx] = base + pre[j];
        }
        __syncthreads();
    }
}

// fused finalize: pos(+sentinel)+rksrc for flags; bcsr/bcur(+sentinel) for buckets
__global__ void k_scan3d(int* __restrict__ pos, const int* __restrict__ bbasA,
                         const int* __restrict__ flag, int NN, int N,
                         int* __restrict__ rksrc,
                         int* __restrict__ bcsr, int* __restrict__ bcur,
                         const int* __restrict__ bbasB, int B2, int E2) {
    int i = blockIdx.x * 256 + threadIdx.x;
    if (i < NN) {
        int v = pos[i] + bbasA[i >> 8];
        pos[i] = v;
        if (i == NN - 1) pos[NN] = v + flag[i];
        if (flag[i]) {
            int slot = i / N;
            rksrc[v] = i - slot * N;
        }
    }
    if (i < B2) {
        int v = bcsr[i] + bbasB[i >> 8];
        bcsr[i] = v;
        bcur[i] = v;
    }
    if (i == 0) bcsr[B2] = E2;
}

// Compacted GEMM + optional fused edge-scatter blocks (bx < nScat, placed first).
// 128x128 tile (4 waves x 64x64), K=256, mtile-major block order, swapped operands.
// LDS: XOR-swizzled (chunk c of row r at c^(r&7)) -> no padding, 32 KB -> 5 blocks/CU
// via the LDS limit. launch_bounds 2nd arg kept at 4: a higher value caps VGPRs below
// the 64 the accumulator tile needs and forces scratch spills (round-17 regression).
__global__ __launch_bounds__(256, 4) void k_T(
    const u16* __restrict__ xb, const u16* __restrict__ Wb, const float* __restrict__ ba,
    const int* __restrict__ pos, const int* __restrict__ rksrc, u16* __restrict__ T,
    int N, int gslot0, int Sg,
    const int* __restrict__ dep, const int* __restrict__ rel, const int* __restrict__ gov,
    int E, int SG, int* __restrict__ bcur, int* __restrict__ epay, int nScat) {
    __shared__ u16 sm[2 * 128 * 64];     // As | Bs, swizzled; reused for transpose
    u16* As = sm;
    u16* Bs = sm + 128 * 64;

    const int tid = threadIdx.x;
    if ((int)blockIdx.x < nScat) {
        // ---- scatter role: payload = group-local compacted T row ----
        int i = blockIdx.x * 256 + tid;
        int st = nScat * 256;
        for (; i < E; i += st) {
            int r = rel[i], d = dep[i], g = gov[i];
            int g0 = r / SG;
            int p = atomicAdd(&bcur[g0 * N + d], 1);
            epay[p] = pos[r * N + g] - pos[g0 * SG * N];
            int gs = 13 + r;
            int g1 = gs / SG;
            int q = atomicAdd(&bcur[g1 * N + g], 1);
            epay[q] = pos[gs * N + d] - pos[g1 * SG * N];
        }
        return;
    }

    const int bx = blockIdx.x - nScat;
    const int mtile = bx / (2 * Sg);
    const int rem = bx - mtile * 2 * Sg;
    const int slot = rem >> 1;
    const int n0 = (rem & 1) * 128;
    const int gslot = gslot0 + slot;
    const int u0 = pos[gslot * N];
    const int used = pos[(gslot + 1) * N] - u0;
    const int row0 = mtile * 128;
    if (row0 >= used) return;
    const int gbase = pos[gslot0 * N];

    const int lane = tid & 63, wv = tid >> 6;
    const int wr = wv & 1, wc = wv >> 1;
    const int l15 = lane & 15, quad = lane >> 4;
    const int srow = tid >> 1, sh = (tid & 1) * 32;

    // per-thread source row (no LDS broadcast needed: only this thread stages srow)
    int arow = row0 + srow;
    if (arow >= used) arow = used - 1;
    const int asrc = rksrc[u0 + arow];
    const u16* agp = xb + (size_t)asrc * DD + sh;
    const u16* bgp = Wb + ((size_t)gslot << 16) + (size_t)(n0 + srow) * DD + sh;

    const int sc0 = sh >> 3;          // first logical chunk (0 or 4)
    const int sx = srow & 7;
    int so[4];                        // physical u16 offsets for the 4 staged chunks
    #pragma unroll
    for (int c = 0; c < 4; ++c) so[c] = srow * 64 + (((sc0 + c) ^ sx) << 3);

    f32x4 acc[4][4] = {};   // acc[nt][mt] = D[n-tile][m-tile] (swapped operands)
    for (int kb = 0; kb < DD; kb += 64) {
        {
            const us8* ga = (const us8*)(agp + kb);
            us8 a0 = ga[0], a1 = ga[1], a2 = ga[2], a3 = ga[3];
            *(us8*)&As[so[0]] = a0;
            *(us8*)&As[so[1]] = a1;
            *(us8*)&As[so[2]] = a2;
            *(us8*)&As[so[3]] = a3;
            const us8* gb = (const us8*)(bgp + kb);
            us8 b0 = gb[0], b1 = gb[1], b2 = gb[2], b3 = gb[3];
            *(us8*)&Bs[so[0]] = b0;
            *(us8*)&Bs[so[1]] = b1;
            *(us8*)&Bs[so[2]] = b2;
            *(us8*)&Bs[so[3]] = b3;
        }
        __syncthreads();
        #pragma unroll
        for (int ks = 0; ks < 2; ++ks) {
            const int ck = ks * 4 + quad;             // logical chunk of this frag
            bf16x8 af[4], bfv[4];
            #pragma unroll
            for (int mt = 0; mt < 4; ++mt) {
                int r = wr * 64 + mt * 16 + l15;
                af[mt] = __builtin_bit_cast(bf16x8,
                    *(const us8*)&As[r * 64 + ((ck ^ (r & 7)) << 3)]);
            }
            #pragma unroll
            for (int nt = 0; nt < 4; ++nt) {
                int r = wc * 64 + nt * 16 + l15;
                bfv[nt] = __builtin_bit_cast(bf16x8,
                    *(const us8*)&Bs[r * 64 + ((ck ^ (r & 7)) << 3)]);
            }
            #pragma unroll
            for (int nt = 0; nt < 4; ++nt)
                #pragma unroll
                for (int mt = 0; mt < 4; ++mt)
                    acc[nt][mt] = __builtin_amdgcn_mfma_f32_16x16x32_bf16(
                        bfv[nt], af[mt], acc[nt][mt], 0, 0, 0);
        }
        __syncthreads();
    }

    // epilogue: +bias (f32x4), bf16, swizzled b64 LDS transpose, b128 global stores
    f32x4 bb[4];
    #pragma unroll
    for (int nt = 0; nt < 4; ++nt)
        bb[nt] = *(const f32x4*)(ba + gslot * DD + n0 + wc * 64 + nt * 16 + quad * 4);
    u16* trb = sm + wv * 4096;        // per-wave 64 rows x 64 cols, swizzled
    #pragma unroll
    for (int mt = 0; mt < 4; ++mt) {
        int m = mt * 16 + l15;
        int mx = m & 7;
        #pragma unroll
        for (int nt = 0; nt < 4; ++nt) {
            us4 t4;
            #pragma unroll
            for (int j = 0; j < 4; ++j) t4[j] = f2bf(acc[nt][mt][j] + bb[nt][j]);
            int col = nt * 16 + quad * 4;
            *(us4*)&trb[m * 64 + (((col >> 3) ^ mx) << 3) + (col & 7)] = t4;
        }
    }
    __syncthreads();
    const int trow0 = u0 - gbase + row0 + wr * 64;
    const int half = lane & 1;
    #pragma unroll
    for (int it = 0; it < 2; ++it) {
        int r = it * 32 + (lane >> 1);
        if (row0 + wr * 64 + r < used) {
            int rx = r & 7;
            us8 v0 = *(const us8*)&trb[r * 64 + (((half * 4 + 0) ^ rx) << 3)];
            us8 v1 = *(const us8*)&trb[r * 64 + (((half * 4 + 1) ^ rx) << 3)];
            us8 v2 = *(const us8*)&trb[r * 64 + (((half * 4 + 2) ^ rx) << 3)];
            us8 v3 = *(const us8*)&trb[r * 64 + (((half * 4 + 3) ^ rx) << 3)];
            us8* dp = (us8*)(T + (size_t)(trow0 + r) * DD + n0 + wc * 64 + half * 32);
            dp[0] = v0; dp[1] = v1; dp[2] = v2; dp[3] = v3;
        }
    }
}

// Gather: one wave per node; lane owns 4 feats; 8-deep load unroll for MLP.
__global__ __launch_bounds__(256) void k_gather(
    const u16* __restrict__ T, const int* __restrict__ epay,
    const int* __restrict__ csr, const int* __restrict__ pos,
    float* __restrict__ out, int N, int bktBase, int selfKeyBase, int gfN,
    int first, int last) {
    int wid = (blockIdx.x * 256 + threadIdx.x) >> 6;
    if (wid >= N) return;
    int feat = (threadIdx.x & 63) * 4;
    f32x4 a = {0.0f, 0.0f, 0.0f, 0.0f};
    if (!first) a = *(const f32x4*)(out + (size_t)wid * DD + feat);
    if (selfKeyBase >= 0) {
        int p = pos[selfKeyBase + wid] - pos[gfN];
        us4 v = *(const us4*)(T + (size_t)p * DD + feat);
        a[0] += bf2f(v[0]); a[1] += bf2f(v[1]); a[2] += bf2f(v[2]); a[3] += bf2f(v[3]);
    }
    int beg = csr[bktBase + wid], end = csr[bktBase + wid + 1];
    f32x4 b = {0, 0, 0, 0}, c = {0, 0, 0, 0}, d4 = {0, 0, 0, 0};
    int j = beg;
    for (; j + 7 < end; j += 8) {
        int p0 = epay[j],     p1 = epay[j + 1], p2 = epay[j + 2], p3 = epay[j + 3];
        int p4 = epay[j + 4], p5 = epay[j + 5], p6 = epay[j + 6], p7 = epay[j + 7];
        us4 v0 = *(const us4*)(T + (size_t)p0 * DD + feat);
        us4 v1 = *(const us4*)(T + (size_t)p1 * DD + feat);
        us4 v2 = *(const us4*)(T + (size_t)p2 * DD + feat);
        us4 v3 = *(const us4*)(T + (size_t)p3 * DD + feat);
        us4 v4 = *(const us4*)(T + (size_t)p4 * DD + feat);
        us4 v5 = *(const us4*)(T + (size_t)p5 * DD + feat);
        us4 v6 = *(const us4*)(T + (size_t)p6 * DD + feat);
        us4 v7 = *(const us4*)(T + (size_t)p7 * DD + feat);
        #pragma unroll
        for (int t = 0; t < 4; ++t) {
            a[t]  += bf2f(v0[t]) + bf2f(v4[t]);
            b[t]  += bf2f(v1[t]) + bf2f(v5[t]);
            c[t]  += bf2f(v2[t]) + bf2f(v6[t]);
            d4[t] += bf2f(v3[t]) + bf2f(v7[t]);
        }
    }
    for (; j + 1 < end; j += 2) {
        int p0 = epay[j], p1 = epay[j + 1];
        us4 v0 = *(const us4*)(T + (size_t)p0 * DD + feat);
        us4 v1 = *(const us4*)(T + (size_t)p1 * DD + feat);
        #pragma unroll
        for (int t = 0; t < 4; ++t) { a[t] += bf2f(v0[t]); b[t] += bf2f(v1[t]); }
    }
    if (j < end) {
        int p0 = epay[j];
        us4 v0 = *(const us4*)(T + (size_t)p0 * DD + feat);
        #pragma unroll
        for (int t = 0; t < 4; ++t) a[t] += bf2f(v0[t]);
    }
    #pragma unroll
    for (int t = 0; t < 4; ++t) a[t] += b[t] + c[t] + d4[t];
    if (last) {
        #pragma unroll
        for (int t = 0; t < 4; ++t) a[t] = fmaxf(a[t], 0.0f);
    }
    *(f32x4*)(out + (size_t)wid * DD + feat) = a;
}

extern "C" void kernel_launch(void* const* d_in, const int* in_sizes, int n_in,
                              void* d_out, int out_size, void* d_ws, size_t ws_size,
                              hipStream_t stream) {
    const float* x      = (const float*)d_in[0];
    const int*   dep    = (const int*)  d_in[1];
    const int*   rel    = (const int*)  d_in[2];
    const int*   gov    = (const int*)  d_in[3];
    const float* W_self = (const float*)d_in[4];
    const float* b_self = (const float*)d_in[5];
    const float* W_rel  = (const float*)d_in[6];
    const float* b_rel  = (const float*)d_in[7];
    float* out = (float*)d_out;

    const int N  = in_sizes[0] / DD;     // 20000
    const int E  = in_sizes[1];          // 200000
    const int NN = NSLOT * N;            // 500000 keys

    char* w = (char*)d_ws;
    auto alloc = [&](size_t bytes) {
        char* p = w;
        w += (bytes + 255) & ~(size_t)255;
        return p;
    };
    u16* xb    = (u16*)alloc((size_t)N * DD * sizeof(u16));
    u16* Wb    = (u16*)alloc((size_t)NSLOT * DD * DD * sizeof(u16));
    float* ba  = (float*)alloc((size_t)NSLOT * DD * sizeof(float));
    int* flag  = (int*)alloc((size_t)NN * sizeof(int));
    int* pos   = (int*)alloc(((size_t)NN + 1) * sizeof(int));
    int* rksrc = (int*)alloc(((size_t)2 * E + N) * sizeof(int));
    int* bcnt  = (int*)alloc((size_t)6 * N * sizeof(int));
    int* bcsr  = (int*)alloc(((size_t)6 * N + 1) * sizeof(int));
    int* bcur  = (int*)alloc((size_t)6 * N * sizeof(int));
    int* bsumA = (int*)alloc((size_t)2048 * sizeof(int));
    int* bbasA = (int*)alloc((size_t)2048 * sizeof(int));
    int* bsumB = (int*)alloc((size_t)2048 * sizeof(int));
    int* bbasB = (int*)alloc((size_t)2048 * sizeof(int));
    int* epay  = (int*)alloc((size_t)2 * E * sizeof(int));

    size_t used = (size_t)(w - (char*)d_ws);
    size_t avail = (ws_size > used) ? (ws_size - used) : 0;

    // choose group count: tight worst-case T rows per group (prefer 1 group)
    int NGROUP = 2, SG = 13;
    for (int ng = 1; ng <= 5; ++ng) {
        int sg = (NSLOT + ng - 1) / ng;
        size_t maxB = 0;
        for (int g = 0; g < ng; ++g) {
            int s0 = g * sg, s1 = s0 + sg; if (s1 > NSLOT) s1 = NSLOT;
            if (s0 >= NSLOT) break;
            int hasSelf = (s0 <= SELFSLOT && SELFSLOT < s1) ? 1 : 0;
            size_t rels = (size_t)(s1 - s0 - hasSelf);
            size_t rows = rels * N; if (rows > (size_t)2 * E) rows = (size_t)2 * E;
            rows += hasSelf ? (size_t)N : 0;
            if (rows > maxB) maxB = rows;
        }
        if (maxB * ((size_t)DD * 2) <= avail) { NGROUP = ng; SG = sg; break; }
        NGROUP = ng + 1; SG = (NSLOT + NGROUP - 1) / NGROUP;
    }
    u16* T = (u16*)w;
    const int B2 = NGROUP * N;

    // 1. zero via DMA, then fused converts ∥ mark+hist (1 dispatch)
    hipMemsetAsync(flag, 0, (size_t)NN * sizeof(int), stream);
    hipMemsetAsync(bcnt, 0, (size_t)B2 * sizeof(int), stream);
    k_prep<<<1536, 256, 0, stream>>>(x, W_rel, W_self, b_self, b_rel, xb, Wb, ba,
                                     dep, rel, gov, E, N, SG, flag, bcnt, N * DD);

    // 2. dual scan: flags (NN) + buckets (B2)
    const int nbA = (NN + 255) / 256;
    const int nbB = (B2 + 255) / 256;
    k_scan1d<<<nbA + nbB, 256, 0, stream>>>(flag, pos, bsumA, NN, nbA, bcnt, bcsr, bsumB, B2);
    k_scan2d<<<1, 256, 0, stream>>>(bsumA, bbasA, nbA, bsumB, bbasB, nbB);
    k_scan3d<<<nbA, 256, 0, stream>>>(pos, bbasA, flag, NN, N, rksrc, bcsr, bcur, bbasB, B2, 2 * E);

    // 3. per group: compacted GEMM (scatter fused into first dispatch) -> gather (+relu last)
    const int tilesPerSlot = (N + 127) / 128;
    const int gBlocks = (N + 3) / 4;
    for (int g = 0; g < NGROUP; ++g) {
        int s0 = g * SG;
        if (s0 >= NSLOT) break;
        int Sg = NSLOT - s0; if (Sg > SG) Sg = SG;
        int nScat = (g == 0) ? 256 : 0;
        k_T<<<dim3(nScat + tilesPerSlot * Sg * 2), 256, 0, stream>>>(
            xb, Wb, ba, pos, rksrc, T, N, s0, Sg,
            dep, rel, gov, E, SG, bcur, epay, nScat);
        int hasSelf = (s0 <= SELFSLOT && SELFSLOT < s0 + Sg);
        k_gather<<<gBlocks, 256, 0, stream>>>(
            T, epay, bcsr, pos, out, N, g * N,
            hasSelf ? SELFSLOT * N : -1, s0 * N,
            (g == 0) ? 1 : 0, (g == NGROUP - 1) ? 1 : 0);
    }
}

// Round 19
// 247.824 us; speedup vs baseline: 1.2443x; 1.0106x over previous
//
#include <hip/hip_runtime.h>
#include <cstdint>
#include <cstddef>

#define DD 256
#define NSLOT 25      // gslot: 0..11 fwd rel | 12 self | 13..24 rev rel
#define SELFSLOT 12

typedef unsigned short u16;
typedef __bf16 bf16t;
typedef bf16t bf16x8 __attribute__((ext_vector_type(8)));
typedef unsigned short us8 __attribute__((ext_vector_type(8)));
typedef unsigned short us4 __attribute__((ext_vector_type(4)));
typedef float f32x4 __attribute__((ext_vector_type(4)));

__device__ __forceinline__ u16 f2bf(float f) {
    uint32_t u = __builtin_bit_cast(uint32_t, f);
    u += 0x7FFFu + ((u >> 16) & 1u);   // RNE
    return (u16)(u >> 16);
}
__device__ __forceinline__ float bf2f(u16 h) {
    uint32_t u = ((uint32_t)h) << 16;
    return __builtin_bit_cast(float, u);
}

// fused prep: blocks [0,1024) convert x/W/bias (float4-vectorized);
// blocks [1024,1536) mark+hist edge pass
__global__ void k_prep(const float* __restrict__ x, const float* __restrict__ W_rel,
                       const float* __restrict__ W_self, const float* __restrict__ b_self,
                       const float* __restrict__ b_rel,
                       u16* __restrict__ xb, u16* __restrict__ Wb, float* __restrict__ ba,
                       const int* __restrict__ dep, const int* __restrict__ rel,
                       const int* __restrict__ gov, int E, int N, int SG,
                       int* __restrict__ flag, int* __restrict__ bcnt, int NDD) {
    if (blockIdx.x < 1024) {
        const int s0 = NDD;                 // x
        const int s1 = s0 + 12 * 65536;     // W_rel fwd
        const int s2 = s1 + 65536;          // W_self
        const int s3 = s2 + 12 * 65536;     // W_rel rev
        const int s4 = s3 + NSLOT * DD;     // bias (all boundaries %4 == 0)
        const int t4 = s4 >> 2;
        int i = blockIdx.x * 256 + threadIdx.x;
        const int st = 1024 * 256;
        for (; i < t4; i += st) {
            int e = i << 2;
            const float* src; u16* dst;
            if (e < s0)      { src = x + e;                    dst = xb + e; }
            else if (e < s1) { src = W_rel + (e - s0);         dst = Wb + (e - s0); }
            else if (e < s2) { src = W_self + (e - s1);        dst = Wb + 12 * 65536 + (e - s1); }
            else if (e < s3) { src = W_rel + 12 * 65536 + (e - s2); dst = Wb + 13 * 65536 + (e - s2); }
            else {
                int k = e - s3;   // bias: sub-boundaries 3072, 3328 are %4 == 0
                const float* bsrc;
                if (k < 12 * DD) bsrc = b_rel + k;
                else if (k < 13 * DD) bsrc = b_self + (k - 12 * DD);
                else bsrc = b_rel + (k - DD);
                *(f32x4*)(ba + k) = *(const f32x4*)bsrc;
                continue;
            }
            f32x4 v = *(const f32x4*)src;
            us4 o;
            #pragma unroll
            for (int j = 0; j < 4; ++j) o[j] = f2bf(v[j]);
            *(us4*)dst = o;
        }
    } else {
        int i = (blockIdx.x - 1024) * 256 + threadIdx.x;
        int st = 512 * 256;
        for (int j = i; j < E; j += st) {
            int r = rel[j], d = dep[j], g = gov[j];
            flag[r * N + g] = 1;
            flag[(13 + r) * N + d] = 1;
            atomicAdd(&bcnt[(r / SG) * N + d], 1);
            atomicAdd(&bcnt[((13 + r) / SG) * N + g], 1);
        }
        for (int j = i; j < N; j += st) flag[SELFSLOT * N + j] = 1;
    }
}

// dual per-block local scan: blocks [0,nbA) scan A (len lenA), rest scan B (len lenB)
__global__ void k_scan1d(const int* __restrict__ A, int* __restrict__ outA,
                         int* __restrict__ bsumA, int lenA, int nbA,
                         const int* __restrict__ B, int* __restrict__ outB,
                         int* __restrict__ bsumB, int lenB) {
    __shared__ int sm[256];
    const int* in; int* outp; int* bs; int len; int lb;
    if ((int)blockIdx.x < nbA) { in = A; outp = outA; bs = bsumA; len = lenA; lb = blockIdx.x; }
    else { in = B; outp = outB; bs = bsumB; len = lenB; lb = blockIdx.x - nbA; }
    int tid = threadIdx.x;
    int i = lb * 256 + tid;
    int v = (i < len) ? in[i] : 0;
    sm[tid] = v;
    __syncthreads();
    for (int off = 1; off < 256; off <<= 1) {
        int t = (tid >= off) ? sm[tid - off] : 0;
        __syncthreads();
        sm[tid] += t;
        __syncthreads();
    }
    if (i < len) outp[i] = sm[tid] - v;
    if (tid == 255) bs[lb] = sm[255];
}

// single block scans both block-total arrays (each <= 2048)
__global__ void k_scan2d(const int* __restrict__ bsumA, int* __restrict__ bbasA, int nbA,
                         const int* __restrict__ bsumB, int* __restrict__ bbasB, int nbB) {
    __shared__ int sm[256];
    int t = threadIdx.x;
    for (int which = 0; which < 2; ++which) {
        const int* bsum = which ? bsumB : bsumA;
        int* bbase = which ? bbasB : bbasA;
        int nb = which ? nbB : nbA;
        int pre[8];
        int tot = 0;
        for (int j = 0; j < 8; ++j) {
            int idx = t * 8 + j;
            int v = (idx < nb) ? bsum[idx] : 0;
            pre[j] = tot;
            tot += v;
        }
        sm[t] = tot;
        __syncthreads();
        for (int off = 1; off < 256; off <<= 1) {
            int x = (t >= off) ? sm[t - off] : 0;
            __syncthreads();
            sm[t] += x;
            __syncthreads();
        }
        int base = sm[t] - tot;
        for (int j = 0; j < 8; ++j) {
            int idx = t * 8 + j;
            if (idx < nb) bbase[idx] = base + pre[j];
        }
        __syncthreads();
    }
}

// fused finalize: pos(+sentinel)+rksrc for flags; bcsr/bcur(+sentinel) for buckets
__global__ void k_scan3d(int* __restrict__ pos, const int* __restrict__ bbasA,
                         const int* __restrict__ flag, int NN, int N,
                         int* __restrict__ rksrc,
                         int* __restrict__ bcsr, int* __restrict__ bcur,
                         const int* __restrict__ bbasB, int B2, int E2) {
    int i = blockIdx.x * 256 + threadIdx.x;
    if (i < NN) {
        int v = pos[i] + bbasA[i >> 8];
        pos[i] = v;
        if (i == NN - 1) pos[NN] = v + flag[i];
        if (flag[i]) {
            int slot = i / N;
            rksrc[v] = i - slot * N;
        }
    }
    if (i < B2) {
        int v = bcsr[i] + bbasB[i >> 8];
        bcsr[i] = v;
        bcur[i] = v;
    }
    if (i == 0) bcsr[B2] = E2;
}

// Compacted GEMM + optional fused edge-scatter blocks (bx < nScat, placed first).
// 128x128 tile (4 waves x 64x64), K=256, mtile-major block order, swapped operands.
// LDS: XOR-swizzled, 32 KB. Register software-pipeline: next K-slab preloaded into
// VGPRs during MFMA so the barrier no longer drains cold global loads.
__global__ __launch_bounds__(256, 4) void k_T(
    const u16* __restrict__ xb, const u16* __restrict__ Wb, const float* __restrict__ ba,
    const int* __restrict__ pos, const int* __restrict__ rksrc, u16* __restrict__ T,
    int N, int gslot0, int Sg,
    const int* __restrict__ dep, const int* __restrict__ rel, const int* __restrict__ gov,
    int E, int SG, int* __restrict__ bcur, int* __restrict__ epay, int nScat) {
    __shared__ u16 sm[2 * 128 * 64];     // As | Bs, swizzled; reused for transpose
    u16* As = sm;
    u16* Bs = sm + 128 * 64;

    const int tid = threadIdx.x;
    if ((int)blockIdx.x < nScat) {
        // ---- scatter role: payload = group-local compacted T row ----
        int i = blockIdx.x * 256 + tid;
        int st = nScat * 256;
        for (; i < E; i += st) {
            int r = rel[i], d = dep[i], g = gov[i];
            int g0 = r / SG;
            int p = atomicAdd(&bcur[g0 * N + d], 1);
            epay[p] = pos[r * N + g] - pos[g0 * SG * N];
            int gs = 13 + r;
            int g1 = gs / SG;
            int q = atomicAdd(&bcur[g1 * N + g], 1);
            epay[q] = pos[gs * N + d] - pos[g1 * SG * N];
        }
        return;
    }

    const int bx = blockIdx.x - nScat;
    const int mtile = bx / (2 * Sg);
    const int rem = bx - mtile * 2 * Sg;
    const int slot = rem >> 1;
    const int n0 = (rem & 1) * 128;
    const int gslot = gslot0 + slot;
    const int u0 = pos[gslot * N];
    const int used = pos[(gslot + 1) * N] - u0;
    const int row0 = mtile * 128;
    if (row0 >= used) return;
    const int gbase = pos[gslot0 * N];

    const int lane = tid & 63, wv = tid >> 6;
    const int wr = wv & 1, wc = wv >> 1;
    const int l15 = lane & 15, quad = lane >> 4;
    const int srow = tid >> 1, sh = (tid & 1) * 32;

    // per-thread source row (no LDS broadcast needed: only this thread stages srow)
    int arow = row0 + srow;
    if (arow >= used) arow = used - 1;
    const int asrc = rksrc[u0 + arow];
    const u16* agp = xb + (size_t)asrc * DD + sh;
    const u16* bgp = Wb + ((size_t)gslot << 16) + (size_t)(n0 + srow) * DD + sh;

    const int sc0 = sh >> 3;          // first logical chunk (0 or 4)
    const int sx = srow & 7;
    int so[4];                        // physical u16 offsets for the 4 staged chunks
    #pragma unroll
    for (int c = 0; c < 4; ++c) so[c] = srow * 64 + (((sc0 + c) ^ sx) << 3);

    // preload slab 0 into registers
    us8 ra0, ra1, ra2, ra3, rb0, rb1, rb2, rb3;
    {
        const us8* ga = (const us8*)agp;
        ra0 = ga[0]; ra1 = ga[1]; ra2 = ga[2]; ra3 = ga[3];
        const us8* gb = (const us8*)bgp;
        rb0 = gb[0]; rb1 = gb[1]; rb2 = gb[2]; rb3 = gb[3];
    }

    f32x4 acc[4][4] = {};   // acc[nt][mt] = D[n-tile][m-tile] (swapped operands)
    #pragma unroll
    for (int kb = 0; kb < DD; kb += 64) {
        *(us8*)&As[so[0]] = ra0;
        *(us8*)&As[so[1]] = ra1;
        *(us8*)&As[so[2]] = ra2;
        *(us8*)&As[so[3]] = ra3;
        *(us8*)&Bs[so[0]] = rb0;
        *(us8*)&Bs[so[1]] = rb1;
        *(us8*)&Bs[so[2]] = rb2;
        *(us8*)&Bs[so[3]] = rb3;
        __syncthreads();
        if (kb + 64 < DD) {   // prefetch next slab; latency hides behind MFMA below
            const us8* ga = (const us8*)(agp + kb + 64);
            ra0 = ga[0]; ra1 = ga[1]; ra2 = ga[2]; ra3 = ga[3];
            const us8* gb = (const us8*)(bgp + kb + 64);
            rb0 = gb[0]; rb1 = gb[1]; rb2 = gb[2]; rb3 = gb[3];
        }
        #pragma unroll
        for (int ks = 0; ks < 2; ++ks) {
            const int ck = ks * 4 + quad;             // logical chunk of this frag
            bf16x8 af[4], bfv[4];
            #pragma unroll
            for (int mt = 0; mt < 4; ++mt) {
                int r = wr * 64 + mt * 16 + l15;
                af[mt] = __builtin_bit_cast(bf16x8,
                    *(const us8*)&As[r * 64 + ((ck ^ (r & 7)) << 3)]);
            }
            #pragma unroll
            for (int nt = 0; nt < 4; ++nt) {
                int r = wc * 64 + nt * 16 + l15;
                bfv[nt] = __builtin_bit_cast(bf16x8,
                    *(const us8*)&Bs[r * 64 + ((ck ^ (r & 7)) << 3)]);
            }
            #pragma unroll
            for (int nt = 0; nt < 4; ++nt)
                #pragma unroll
                for (int mt = 0; mt < 4; ++mt)
                    acc[nt][mt] = __builtin_amdgcn_mfma_f32_16x16x32_bf16(
                        bfv[nt], af[mt], acc[nt][mt], 0, 0, 0);
        }
        __syncthreads();
    }

    // epilogue: +bias (f32x4), bf16, swizzled b64 LDS transpose, b128 global stores
    f32x4 bb[4];
    #pragma unroll
    for (int nt = 0; nt < 4; ++nt)
        bb[nt] = *(const f32x4*)(ba + gslot * DD + n0 + wc * 64 + nt * 16 + quad * 4);
    u16* trb = sm + wv * 4096;        // per-wave 64 rows x 64 cols, swizzled
    #pragma unroll
    for (int mt = 0; mt < 4; ++mt) {
        int m = mt * 16 + l15;
        int mx = m & 7;
        #pragma unroll
        for (int nt = 0; nt < 4; ++nt) {
            us4 t4;
            #pragma unroll
            for (int j = 0; j < 4; ++j) t4[j] = f2bf(acc[nt][mt][j] + bb[nt][j]);
            int col = nt * 16 + quad * 4;
            *(us4*)&trb[m * 64 + (((col >> 3) ^ mx) << 3) + (col & 7)] = t4;
        }
    }
    __syncthreads();
    const int trow0 = u0 - gbase + row0 + wr * 64;
    const int half = lane & 1;
    #pragma unroll
    for (int it = 0; it < 2; ++it) {
        int r = it * 32 + (lane >> 1);
        if (row0 + wr * 64 + r < used) {
            int rx = r & 7;
            us8 v0 = *(const us8*)&trb[r * 64 + (((half * 4 + 0) ^ rx) << 3)];
            us8 v1 = *(const us8*)&trb[r * 64 + (((half * 4 + 1) ^ rx) << 3)];
            us8 v2 = *(const us8*)&trb[r * 64 + (((half * 4 + 2) ^ rx) << 3)];
            us8 v3 = *(const us8*)&trb[r * 64 + (((half * 4 + 3) ^ rx) << 3)];
            us8* dp = (us8*)(T + (size_t)(trow0 + r) * DD + n0 + wc * 64 + half * 32);
            dp[0] = v0; dp[1] = v1; dp[2] = v2; dp[3] = v3;
        }
    }
}

// Gather: one wave per node; lane owns 4 feats; 8-deep load unroll for MLP.
__global__ __launch_bounds__(256) void k_gather(
    const u16* __restrict__ T, const int* __restrict__ epay,
    const int* __restrict__ csr, const int* __restrict__ pos,
    float* __restrict__ out, int N, int bktBase, int selfKeyBase, int gfN,
    int first, int last) {
    int wid = (blockIdx.x * 256 + threadIdx.x) >> 6;
    if (wid >= N) return;
    int feat = (threadIdx.x & 63) * 4;
    f32x4 a = {0.0f, 0.0f, 0.0f, 0.0f};
    if (!first) a = *(const f32x4*)(out + (size_t)wid * DD + feat);
    if (selfKeyBase >= 0) {
        int p = pos[selfKeyBase + wid] - pos[gfN];
        us4 v = *(const us4*)(T + (size_t)p * DD + feat);
        a[0] += bf2f(v[0]); a[1] += bf2f(v[1]); a[2] += bf2f(v[2]); a[3] += bf2f(v[3]);
    }
    int beg = csr[bktBase + wid], end = csr[bktBase + wid + 1];
    f32x4 b = {0, 0, 0, 0}, c = {0, 0, 0, 0}, d4 = {0, 0, 0, 0};
    int j = beg;
    for (; j + 7 < end; j += 8) {
        int p0 = epay[j],     p1 = epay[j + 1], p2 = epay[j + 2], p3 = epay[j + 3];
        int p4 = epay[j + 4], p5 = epay[j + 5], p6 = epay[j + 6], p7 = epay[j + 7];
        us4 v0 = *(const us4*)(T + (size_t)p0 * DD + feat);
        us4 v1 = *(const us4*)(T + (size_t)p1 * DD + feat);
        us4 v2 = *(const us4*)(T + (size_t)p2 * DD + feat);
        us4 v3 = *(const us4*)(T + (size_t)p3 * DD + feat);
        us4 v4 = *(const us4*)(T + (size_t)p4 * DD + feat);
        us4 v5 = *(const us4*)(T + (size_t)p5 * DD + feat);
        us4 v6 = *(const us4*)(T + (size_t)p6 * DD + feat);
        us4 v7 = *(const us4*)(T + (size_t)p7 * DD + feat);
        #pragma unroll
        for (int t = 0; t < 4; ++t) {
            a[t]  += bf2f(v0[t]) + bf2f(v4[t]);
            b[t]  += bf2f(v1[t]) + bf2f(v5[t]);
            c[t]  += bf2f(v2[t]) + bf2f(v6[t]);
            d4[t] += bf2f(v3[t]) + bf2f(v7[t]);
        }
    }
    for (; j + 1 < end; j += 2) {
        int p0 = epay[j], p1 = epay[j + 1];
        us4 v0 = *(const us4*)(T + (size_t)p0 * DD + feat);
        us4 v1 = *(const us4*)(T + (size_t)p1 * DD + feat);
        #pragma unroll
        for (int t = 0; t < 4; ++t) { a[t] += bf2f(v0[t]); b[t] += bf2f(v1[t]); }
    }
    if (j < end) {
        int p0 = epay[j];
        us4 v0 = *(const us4*)(T + (size_t)p0 * DD + feat);
        #pragma unroll
        for (int t = 0; t < 4; ++t) a[t] += bf2f(v0[t]);
    }
    #pragma unroll
    for (int t = 0; t < 4; ++t) a[t] += b[t] + c[t] + d4[t];
    if (last) {
        #pragma unroll
        for (int t = 0; t < 4; ++t) a[t] = fmaxf(a[t], 0.0f);
    }
    *(f32x4*)(out + (size_t)wid * DD + feat) = a;
}

extern "C" void kernel_launch(void* const* d_in, const int* in_sizes, int n_in,
                              void* d_out, int out_size, void* d_ws, size_t ws_size,
                              hipStream_t stream) {
    const float* x      = (const float*)d_in[0];
    const int*   dep    = (const int*)  d_in[1];
    const int*   rel    = (const int*)  d_in[2];
    const int*   gov    = (const int*)  d_in[3];
    const float* W_self = (const float*)d_in[4];
    const float* b_self = (const float*)d_in[5];
    const float* W_rel  = (const float*)d_in[6];
    const float* b_rel  = (const float*)d_in[7];
    float* out = (float*)d_out;

    const int N  = in_sizes[0] / DD;     // 20000
    const int E  = in_sizes[1];          // 200000
    const int NN = NSLOT * N;            // 500000 keys

    char* w = (char*)d_ws;
    auto alloc = [&](size_t bytes) {
        char* p = w;
        w += (bytes + 255) & ~(size_t)255;
        return p;
    };
    u16* xb    = (u16*)alloc((size_t)N * DD * sizeof(u16));
    u16* Wb    = (u16*)alloc((size_t)NSLOT * DD * DD * sizeof(u16));
    float* ba  = (float*)alloc((size_t)NSLOT * DD * sizeof(float));
    // contiguous zero region: flag | bcnt (single memset)
    int* flag  = (int*)alloc((size_t)NN * sizeof(int));
    int* bcnt  = (int*)alloc((size_t)6 * N * sizeof(int));
    char* zend = w;
    int* pos   = (int*)alloc(((size_t)NN + 1) * sizeof(int));
    int* rksrc = (int*)alloc(((size_t)2 * E + N) * sizeof(int));
    int* bcsr  = (int*)alloc(((size_t)6 * N + 1) * sizeof(int));
    int* bcur  = (int*)alloc((size_t)6 * N * sizeof(int));
    int* bsumA = (int*)alloc((size_t)2048 * sizeof(int));
    int* bbasA = (int*)alloc((size_t)2048 * sizeof(int));
    int* bsumB = (int*)alloc((size_t)2048 * sizeof(int));
    int* bbasB = (int*)alloc((size_t)2048 * sizeof(int));
    int* epay  = (int*)alloc((size_t)2 * E * sizeof(int));

    size_t used = (size_t)(w - (char*)d_ws);
    size_t avail = (ws_size > used) ? (ws_size - used) : 0;

    // choose group count: tight worst-case T rows per group (prefer 1 group)
    int NGROUP = 2, SG = 13;
    for (int ng = 1; ng <= 5; ++ng) {
        int sg = (NSLOT + ng - 1) / ng;
        size_t maxB = 0;
        for (int g = 0; g < ng; ++g) {
            int s0 = g * sg, s1 = s0 + sg; if (s1 > NSLOT) s1 = NSLOT;
            if (s0 >= NSLOT) break;
            int hasSelf = (s0 <= SELFSLOT && SELFSLOT < s1) ? 1 : 0;
            size_t rels = (size_t)(s1 - s0 - hasSelf);
            size_t rows = rels * N; if (rows > (size_t)2 * E) rows = (size_t)2 * E;
            rows += hasSelf ? (size_t)N : 0;
            if (rows > maxB) maxB = rows;
        }
        if (maxB * ((size_t)DD * 2) <= avail) { NGROUP = ng; SG = sg; break; }
        NGROUP = ng + 1; SG = (NSLOT + NGROUP - 1) / NGROUP;
    }
    u16* T = (u16*)w;
    const int B2 = NGROUP * N;

    // 1. single memset over flag|bcnt, then fused converts ∥ mark+hist (1 dispatch)
    hipMemsetAsync(flag, 0, (size_t)(zend - (char*)flag), stream);
    k_prep<<<1536, 256, 0, stream>>>(x, W_rel, W_self, b_self, b_rel, xb, Wb, ba,
                                     dep, rel, gov, E, N, SG, flag, bcnt, N * DD);

    // 2. dual scan: flags (NN) + buckets (B2)
    const int nbA = (NN + 255) / 256;
    const int nbB = (B2 + 255) / 256;
    k_scan1d<<<nbA + nbB, 256, 0, stream>>>(flag, pos, bsumA, NN, nbA, bcnt, bcsr, bsumB, B2);
    k_scan2d<<<1, 256, 0, stream>>>(bsumA, bbasA, nbA, bsumB, bbasB, nbB);
    k_scan3d<<<nbA, 256, 0, stream>>>(pos, bbasA, flag, NN, N, rksrc, bcsr, bcur, bbasB, B2, 2 * E);

    // 3. per group: compacted GEMM (scatter fused into first dispatch) -> gather (+relu last)
    const int tilesPerSlot = (N + 127) / 128;
    const int gBlocks = (N + 3) / 4;
    for (int g = 0; g < NGROUP; ++g) {
        int s0 = g * SG;
        if (s0 >= NSLOT) break;
        int Sg = NSLOT - s0; if (Sg > SG) Sg = SG;
        int nScat = (g == 0) ? 256 : 0;
        k_T<<<dim3(nScat + tilesPerSlot * Sg * 2), 256, 0, stream>>>(
            xb, Wb, ba, pos, rksrc, T, N, s0, Sg,
            dep, rel, gov, E, SG, bcur, epay, nScat);
        int hasSelf = (s0 <= SELFSLOT && SELFSLOT < s0 + Sg);
        k_gather<<<gBlocks, 256, 0, stream>>>(
            T, epay, bcsr, pos, out, N, g * N,
            hasSelf ? SELFSLOT * N : -1, s0 * N,
            (g == 0) ? 1 : 0, (g == NGROUP - 1) ? 1 : 0);
    }
}